// Round 2
// baseline (966.481 us; speedup 1.0000x reference)
//
#include <hip/hip_runtime.h>
#include <hip/hip_bf16.h>
#include <math.h>

typedef __bf16 bf16;
typedef __bf16 bf16x8 __attribute__((ext_vector_type(8)));
typedef float f32x4 __attribute__((ext_vector_type(4)));

#define E_ 768
#define S_ 1024
#define BT_ 16
#define KM_ 12
#define KX_ 24
#define NPOS_ 4608
#define NB_ 12

__device__ __forceinline__ float gelu_exact(float x) {
    return 0.5f * x * (1.0f + erff(x * 0.70710678118654752f));
}

// ---------------- LN1 stats only: mu, rstd per row (row = 768) ----------------
__global__ __launch_bounds__(256) void k_ln_stats(const float* __restrict__ x,
                                                  float* __restrict__ mu, float* __restrict__ rs) {
    int row = blockIdx.x;
    int t = threadIdx.x;
    const float* xr = x + (size_t)row * E_;
    float v0 = xr[t], v1 = xr[t + 256], v2 = xr[t + 512];
    float s = v0 + v1 + v2;
    float ss = v0 * v0 + v1 * v1 + v2 * v2;
    for (int off = 32; off > 0; off >>= 1) {
        s  += __shfl_xor(s, off);
        ss += __shfl_xor(ss, off);
    }
    __shared__ float ls[4], lss[4];
    int w = t >> 6, l = t & 63;
    if (l == 0) { ls[w] = s; lss[w] = ss; }
    __syncthreads();
    if (t == 0) {
        s  = ls[0] + ls[1] + ls[2] + ls[3];
        ss = lss[0] + lss[1] + lss[2] + lss[3];
        float m = s * (1.0f / E_);
        float var = ss * (1.0f / E_) - m * m;
        mu[row] = m;
        rs[row] = rsqrtf(var + 1e-5f);
    }
}

// ---------------- full LayerNorm (ln2) -> bf16 ----------------
__global__ __launch_bounds__(256) void k_ln2(const float* __restrict__ x,
                                             const float* __restrict__ g,
                                             const float* __restrict__ b,
                                             bf16* __restrict__ out) {
    int row = blockIdx.x;
    int t = threadIdx.x;
    const float* xr = x + (size_t)row * E_;
    float v0 = xr[t], v1 = xr[t + 256], v2 = xr[t + 512];
    float s = v0 + v1 + v2;
    float ss = v0 * v0 + v1 * v1 + v2 * v2;
    for (int off = 32; off > 0; off >>= 1) {
        s  += __shfl_xor(s, off);
        ss += __shfl_xor(ss, off);
    }
    __shared__ float ls[4], lss[4];
    int w = t >> 6, l = t & 63;
    if (l == 0) { ls[w] = s; lss[w] = ss; }
    __syncthreads();
    s  = ls[0] + ls[1] + ls[2] + ls[3];
    ss = lss[0] + lss[1] + lss[2] + lss[3];
    float m = s * (1.0f / E_);
    float var = ss * (1.0f / E_) - m * m;
    float r = rsqrtf(var + 1e-5f);
    #pragma unroll
    for (int q = 0; q < 3; q++) {
        int e = t + q * 256;
        float v = (q == 0) ? v0 : ((q == 1) ? v1 : v2);
        out[(size_t)row * E_ + e] = (bf16)((v - m) * r * g[e] + b[e]);
    }
}

// ---------------- forward DFT along y (12 modes), LN1 fused on the fly ----------------
__global__ __launch_bounds__(256) void k_dft_y(const float* __restrict__ inp,
                                               const float* __restrict__ mu, const float* __restrict__ rs,
                                               const float* __restrict__ g, const float* __restrict__ bb,
                                               float* __restrict__ gre, float* __restrict__ gim) {
    int bid = blockIdx.x;                 // BT_*32*3
    int ec = bid % 3, x = (bid / 3) % 32, bt = bid / 96;
    int t = threadIdx.x;
    __shared__ float tile[32 * 256];
    __shared__ float c32[32], s32[32];
    if (t < 32) { float a = 6.28318530717958647692f * t / 32.0f; c32[t] = cosf(a); s32[t] = sinf(a); }
    int e = ec * 256 + t;
    float gv = g[e], bv = bb[e];
    int row0 = bt * S_ + x * 32;
    const float* base = inp + (size_t)row0 * E_ + e;
    for (int y = 0; y < 32; y++) {
        float m = mu[row0 + y], r = rs[row0 + y];
        tile[y * 256 + t] = (base[(size_t)y * E_] - m) * r * gv + bv;
    }
    __syncthreads();
    for (int ky = 0; ky < KM_; ky++) {
        float re = 0.f, im = 0.f;
        for (int y = 0; y < 32; y++) {
            int j = (ky * y) & 31;
            float v = tile[y * 256 + t];
            re += v * c32[j];
            im -= v * s32[j];
        }
        size_t o = ((size_t)((bt * 32 + x) * KM_ + ky)) * E_ + e;
        gre[o] = re; gim[o] = im;
    }
}

// ---------------- forward DFT along x (kx=5..28), scale 1/32; 32 KB LDS, 2-stage ----------------
__global__ __launch_bounds__(256) void k_dft_x(const float* __restrict__ gre, const float* __restrict__ gim,
                                               float* __restrict__ fr, float* __restrict__ fi) {
    int bid = blockIdx.x;                 // BT_*KM_*3
    int ec = bid % 3, ky = (bid / 3) % KM_, bt = bid / (3 * KM_);
    int t = threadIdx.x;
    __shared__ float lre[16 * 256];
    __shared__ float lim[16 * 256];
    __shared__ float c32[32], s32[32];
    if (t < 32) { float a = 6.28318530717958647692f * t / 32.0f; c32[t] = cosf(a); s32[t] = sinf(a); }
    float ar[KX_], ai[KX_];
    #pragma unroll
    for (int k = 0; k < KX_; k++) { ar[k] = 0.f; ai[k] = 0.f; }
    for (int half = 0; half < 2; half++) {
        __syncthreads();
        for (int xi = 0; xi < 16; xi++) {
            int x = half * 16 + xi;
            size_t o = ((size_t)((bt * 32 + x) * KM_ + ky)) * E_ + ec * 256 + t;
            lre[xi * 256 + t] = gre[o];
            lim[xi * 256 + t] = gim[o];
        }
        __syncthreads();
        for (int kxi = 0; kxi < KX_; kxi++) {
            int kx = kxi + 5;
            float re = 0.f, im = 0.f;
            #pragma unroll
            for (int xi = 0; xi < 16; xi++) {
                int j = (kx * (half * 16 + xi)) & 31;
                float c = c32[j], s = s32[j];
                float gr = lre[xi * 256 + t], gi = lim[xi * 256 + t];
                re += gr * c + gi * s;          // (gr+i*gi)*(c - i*s)
                im += gi * c - gr * s;
            }
            ar[kxi] += re; ai[kxi] += im;
        }
    }
    #pragma unroll
    for (int kxi = 0; kxi < KX_; kxi++) {
        size_t p = (size_t)(bt * KX_ + kxi) * KM_ + ky;
        fr[p * E_ + ec * 256 + t] = ar[kxi] * (1.0f / 32.0f);
        fi[p * E_ + ec * 256 + t] = ai[kxi] * (1.0f / 32.0f);
    }
}

// ---------------- block-diagonal complex 2-layer MLP + softshrink (IN-PLACE on fr/fi) ----------------
__global__ __launch_bounds__(256) void k_blockmlp(float* fr, float* fi,
                                                  const float* __restrict__ w1, const float* __restrict__ b1,
                                                  const float* __restrict__ w2, const float* __restrict__ b2) {
    int n = blockIdx.x % NB_;
    int pt = blockIdx.x / NB_;            // 72 tiles of 64 positions
    int t = threadIdx.x;
    __shared__ float w1a[4096], w1b[4096], w2a[4096], w2b[4096];
    __shared__ float fre[4][64], fim[4][64], o1r[4][64], o1i[4][64];
    __shared__ float b1r[64], b1i[64], b2r[64], b2i[64];
    for (int i = t; i < 4096; i += 256) {
        w1a[i] = w1[n * 4096 + i];
        w1b[i] = w1[NB_ * 4096 + n * 4096 + i];
        w2a[i] = w2[n * 4096 + i];
        w2b[i] = w2[NB_ * 4096 + n * 4096 + i];
    }
    if (t < 64) {
        b1r[t] = b1[n * 64 + t]; b1i[t] = b1[NB_ * 64 + n * 64 + t];
        b2r[t] = b2[n * 64 + t]; b2i[t] = b2[NB_ * 64 + n * 64 + t];
    }
    int o = t & 63, ps = t >> 6;
    for (int c = 0; c < 16; c++) {
        int p0 = pt * 64 + c * 4;
        __syncthreads();
        for (int f = t; f < 512; f += 256) {
            int pp = f >> 7, idx = f & 127;
            size_t ga = (size_t)(p0 + pp) * E_ + n * 64 + (idx & 63);
            if (idx < 64) fre[pp][idx] = fr[ga];
            else          fim[pp][idx - 64] = fi[ga];
        }
        __syncthreads();
        float ar = b1r[o], ai = b1i[o];
        for (int i = 0; i < 64; i++) {
            float xr = fre[ps][i], xi = fim[ps][i];
            float wa = w1a[i * 64 + o], wb = w1b[i * 64 + o];
            ar += xr * wa - xi * wb;
            ai += xi * wa + xr * wb;
        }
        o1r[ps][o] = gelu_exact(ar);
        o1i[ps][o] = gelu_exact(ai);
        __syncthreads();
        float cr = b2r[o], ci = b2i[o];
        for (int i = 0; i < 64; i++) {
            float xr = o1r[ps][i], xi = o1i[ps][i];
            float wa = w2a[i * 64 + o], wb = w2b[i * 64 + o];
            cr += xr * wa - xi * wb;
            ci += xi * wa + xr * wb;
        }
        cr = (cr > 0.01f) ? cr - 0.01f : ((cr < -0.01f) ? cr + 0.01f : 0.0f);
        ci = (ci > 0.01f) ? ci - 0.01f : ((ci < -0.01f) ? ci + 0.01f : 0.0f);
        size_t ga = (size_t)(p0 + ps) * E_ + n * 64 + o;
        fr[ga] = cr;
        fi[ga] = ci;
    }
}

// ---------------- inverse DFT along x (complex ifft, 24 input modes) ----------------
__global__ __launch_bounds__(256) void k_idft_x(const float* __restrict__ pr_, const float* __restrict__ pi_,
                                                float* __restrict__ zre, float* __restrict__ zim) {
    int bid = blockIdx.x;                 // BT_*KM_*3
    int ec = bid % 3, ky = (bid / 3) % KM_, bt = bid / (3 * KM_);
    int t = threadIdx.x;
    __shared__ float lre[KX_ * 256], lim[KX_ * 256];
    __shared__ float c32[32], s32[32];
    if (t < 32) { float a = 6.28318530717958647692f * t / 32.0f; c32[t] = cosf(a); s32[t] = sinf(a); }
    for (int kxi = 0; kxi < KX_; kxi++) {
        size_t p = (size_t)(bt * KX_ + kxi) * KM_ + ky;
        lre[kxi * 256 + t] = pr_[p * E_ + ec * 256 + t];
        lim[kxi * 256 + t] = pi_[p * E_ + ec * 256 + t];
    }
    __syncthreads();
    for (int x = 0; x < 32; x++) {
        float re = 0.f, im = 0.f;
        for (int kxi = 0; kxi < KX_; kxi++) {
            int kx = kxi + 5;
            int j = (kx * x) & 31;
            float c = c32[j], s = s32[j];
            float pr = lre[kxi * 256 + t], pi = lim[kxi * 256 + t];
            re += pr * c - pi * s;          // (pr+i*pi)*(c + i*s)
            im += pr * s + pi * c;
        }
        size_t zo = ((size_t)((bt * 32 + x) * KM_ + ky)) * E_ + ec * 256 + t;
        zre[zo] = re; zim[zo] = im;
    }
}

// ---------------- inverse rfft along y + residuals: out = spat + ln1(inp) + inp ----------------
__global__ __launch_bounds__(256) void k_idft_y_res(const float* __restrict__ zre, const float* __restrict__ zim,
                                                    const float* __restrict__ inp,
                                                    const float* __restrict__ mu, const float* __restrict__ rs,
                                                    const float* __restrict__ g, const float* __restrict__ bb,
                                                    float* __restrict__ out) {
    int bid = blockIdx.x;                 // BT_*32*3
    int ec = bid % 3, x = (bid / 3) % 32, bt = bid / 96;
    int t = threadIdx.x;
    __shared__ float lre[KM_ * 256], lim[KM_ * 256];
    __shared__ float c32[32], s32[32];
    if (t < 32) { float a = 6.28318530717958647692f * t / 32.0f; c32[t] = cosf(a); s32[t] = sinf(a); }
    for (int ky = 0; ky < KM_; ky++) {
        size_t zo = ((size_t)((bt * 32 + x) * KM_ + ky)) * E_ + ec * 256 + t;
        lre[ky * 256 + t] = zre[zo];
        lim[ky * 256 + t] = zim[zo];
    }
    __syncthreads();
    int e = ec * 256 + t;
    float gv = g[e], bv = bb[e];
    int row0 = bt * S_ + x * 32;
    for (int y = 0; y < 32; y++) {
        float v = lre[t];                 // ky=0: Re only (irfft drops Im of DC)
        for (int ky = 1; ky < KM_; ky++) {
            int j = (ky * y) & 31;
            v += 2.0f * (lre[ky * 256 + t] * c32[j] - lim[ky * 256 + t] * s32[j]);
        }
        v *= (1.0f / 32.0f);
        size_t o = (size_t)(row0 + y) * E_ + e;
        float iv = inp[o];
        float m = mu[row0 + y], r = rs[row0 + y];
        out[o] = v + ((iv - m) * r * gv + bv) + iv;
    }
}

// ---------------- fp32 [R][C] -> bf16 [C][R] transpose+cast ----------------
__global__ void k_transpose_cast(const float* __restrict__ src, bf16* __restrict__ dst, int R, int C) {
    __shared__ float tile[32][33];
    int c0 = blockIdx.x * 32, r0 = blockIdx.y * 32;
    int tx = threadIdx.x, ty = threadIdx.y;
    #pragma unroll
    for (int j = 0; j < 32; j += 8)
        tile[ty + j][tx] = src[(size_t)(r0 + ty + j) * C + c0 + tx];
    __syncthreads();
    #pragma unroll
    for (int j = 0; j < 32; j += 8)
        dst[(size_t)(c0 + ty + j) * R + r0 + tx] = (bf16)tile[tx][ty + j];
}

// ---------------- bf16 MFMA GEMM, 128x128 tile, BK=32 ----------------
// A: [M][K] bf16 row-major.  Bt: [N][K] bf16 (i.e. W^T).  bias: [N] fp32.
// FUSE_GELU: outb[row*N+col] = bf16(gelu(acc+bias))
// else:      outf[row*N+col] = acc + bias + outf[row*N+col]   (in-place residual add)
template<bool FUSE_GELU>
__global__ __launch_bounds__(256) void k_gemm(const bf16* __restrict__ A, const bf16* __restrict__ Bt,
                                              const float* __restrict__ bias, int M, int N, int K,
                                              bf16* __restrict__ outb, float* __restrict__ outf) {
    __shared__ __align__(16) bf16 lA[128 * 32];
    __shared__ __align__(16) bf16 lB[128 * 32];
    int t = threadIdx.x;
    int m0 = blockIdx.x * 128, n0 = blockIdx.y * 128;
    int w = t >> 6, l = t & 63;
    int wm = (w & 1) * 64, wn = (w >> 1) * 64;
    int lr = l & 15, lq = l >> 4;
    f32x4 acc[4][4];
    #pragma unroll
    for (int i = 0; i < 4; i++)
        #pragma unroll
        for (int j = 0; j < 4; j++)
            acc[i][j] = (f32x4){0.f, 0.f, 0.f, 0.f};
    const bf16* gA = A + (size_t)m0 * K;
    const bf16* gB = Bt + (size_t)n0 * K;
    int nk = K / 32;
    for (int kt = 0; kt < nk; kt++) {
        const bf16* pa = gA + kt * 32;
        const bf16* pb = gB + kt * 32;
        #pragma unroll
        for (int q = 0; q < 2; q++) {
            int cid = q * 256 + t;
            int row = cid >> 2, ks = cid & 3;
            *(uint4*)&lA[row * 32 + ks * 8] = *(const uint4*)(pa + (size_t)row * K + ks * 8);
            *(uint4*)&lB[row * 32 + ks * 8] = *(const uint4*)(pb + (size_t)row * K + ks * 8);
        }
        __syncthreads();
        bf16x8 af[4], bfv[4];
        #pragma unroll
        for (int mi = 0; mi < 4; mi++) af[mi]  = *(bf16x8*)&lA[(wm + mi * 16 + lr) * 32 + lq * 8];
        #pragma unroll
        for (int ni = 0; ni < 4; ni++) bfv[ni] = *(bf16x8*)&lB[(wn + ni * 16 + lr) * 32 + lq * 8];
        #pragma unroll
        for (int mi = 0; mi < 4; mi++)
            #pragma unroll
            for (int ni = 0; ni < 4; ni++)
                acc[mi][ni] = __builtin_amdgcn_mfma_f32_16x16x32_bf16(af[mi], bfv[ni], acc[mi][ni], 0, 0, 0);
        __syncthreads();
    }
    #pragma unroll
    for (int mi = 0; mi < 4; mi++) {
        #pragma unroll
        for (int ni = 0; ni < 4; ni++) {
            int col = n0 + wn + ni * 16 + lr;
            float bv = bias[col];
            #pragma unroll
            for (int r = 0; r < 4; r++) {
                int row = m0 + wm + mi * 16 + lq * 4 + r;
                float v = acc[mi][ni][r] + bv;
                if (FUSE_GELU) {
                    outb[(size_t)row * N + col] = (bf16)gelu_exact(v);
                } else {
                    size_t oo = (size_t)row * N + col;
                    outf[oo] = v + outf[oo];
                }
            }
        }
    }
}

extern "C" void kernel_launch(void* const* d_in, const int* in_sizes, int n_in,
                              void* d_out, int out_size, void* d_ws, size_t ws_size,
                              hipStream_t stream) {
    const float* input = (const float*)d_in[0];
    const float* w1    = (const float*)d_in[1];
    const float* b1    = (const float*)d_in[2];
    const float* w2    = (const float*)d_in[3];
    const float* b2    = (const float*)d_in[4];
    const float* ln1g  = (const float*)d_in[5];
    const float* ln1b  = (const float*)d_in[6];
    const float* ln2g  = (const float*)d_in[7];
    const float* ln2b  = (const float*)d_in[8];
    const float* mw1   = (const float*)d_in[9];
    const float* mb1   = (const float*)d_in[10];
    const float* mw2   = (const float*)d_in[11];
    const float* mb2   = (const float*)d_in[12];
    float* out = (float*)d_out;

    // ---- workspace: total 16,547,840 floats = 66.2 MB ----
    // phase 1: [mu|rs | gre | gim | fr | fi]
    // phase 2 (aliases phase-1 region, all phase-1 buffers dead by then):
    //          [mu|rs | lnA(bf16) | w1T | w2T | mid(bf16, 4096x3072)]
    float* ws = (float*)d_ws;
    float* mu  = ws;                       // 16384
    float* rs  = ws + 16384;               // 16384
    const size_t BASE = 32768;
    float* gre = ws + BASE;                // 4,718,592
    float* gim = gre + 4718592;            // 4,718,592
    float* fr  = ws + BASE + 2 * 4718592;  // 3,538,944
    float* fi  = fr + 3538944;             // 3,538,944
    bf16* lnA = (bf16*)(ws + BASE);                  // 12,582,912 bf16 (6,291,456 fl)
    bf16* w1T = (bf16*)(ws + BASE + 6291456);        //  2,359,296 bf16 (1,179,648 fl)
    bf16* w2T = (bf16*)(ws + BASE + 7471104);        //  2,359,296 bf16
    bf16* mid = (bf16*)(ws + BASE + 8650752);        // 12,582,912 bf16 (4096x3072)

    k_ln_stats<<<16384, 256, 0, stream>>>(input, mu, rs);
    k_dft_y<<<BT_ * 32 * 3, 256, 0, stream>>>(input, mu, rs, ln1g, ln1b, gre, gim);
    k_dft_x<<<BT_ * KM_ * 3, 256, 0, stream>>>(gre, gim, fr, fi);
    k_blockmlp<<<NB_ * 72, 256, 0, stream>>>(fr, fi, w1, b1, w2, b2);
    k_idft_x<<<BT_ * KM_ * 3, 256, 0, stream>>>(fr, fi, gre, gim);   // gre/gim now hold Z
    k_idft_y_res<<<BT_ * 32 * 3, 256, 0, stream>>>(gre, gim, input, mu, rs, ln1g, ln1b, out);
    k_ln2<<<16384, 256, 0, stream>>>(out, ln2g, ln2b, lnA);
    k_transpose_cast<<<dim3(3072 / 32, 768 / 32), dim3(32, 8), 0, stream>>>(mw1, w1T, 768, 3072);
    k_transpose_cast<<<dim3(768 / 32, 3072 / 32), dim3(32, 8), 0, stream>>>(mw2, w2T, 3072, 768);
    for (int c = 0; c < 4; c++) {
        const bf16* aC = lnA + (size_t)c * 4096 * 768;
        float* oC = out + (size_t)c * 4096 * 768;
        k_gemm<true><<<dim3(32, 24), 256, 0, stream>>>(aC, w1T, mb1, 4096, 3072, 768, mid, nullptr);
        k_gemm<false><<<dim3(32, 6), 256, 0, stream>>>(mid, w2T, mb2, 4096, 768, 3072, nullptr, oC);
    }
}

// Round 3
// 783.150 us; speedup vs baseline: 1.2341x; 1.2341x over previous
//
#include <hip/hip_runtime.h>
#include <hip/hip_bf16.h>
#include <math.h>

typedef __bf16 bf16;
typedef __bf16 bf16x8 __attribute__((ext_vector_type(8)));
typedef float f32x4 __attribute__((ext_vector_type(4)));
typedef short short8 __attribute__((ext_vector_type(8)));

#define E_ 768
#define S_ 1024
#define BT_ 16
#define KM_ 12
#define KX_ 24
#define NPOS_ 4608
#define NB_ 12

__device__ __forceinline__ float gelu_exact(float x) {
    return 0.5f * x * (1.0f + erff(x * 0.70710678118654752f));
}

// async global->LDS 16B; LDS dest must be wave-uniform base (lane deposits at base+lane*16)
__device__ __forceinline__ void gload16(const bf16* g, bf16* l) {
    __builtin_amdgcn_global_load_lds(
        (const __attribute__((address_space(1))) void*)g,
        (__attribute__((address_space(3))) void*)l,
        16, 0, 0);
}

// negate 8 bf16 lanes (flip sign bits) — MFMA has no subtract-accumulate
__device__ __forceinline__ bf16x8 neg8(bf16x8 v) {
    short8 s;
    __builtin_memcpy(&s, &v, 16);
    s ^= (short)0x8000;
    bf16x8 r;
    __builtin_memcpy(&r, &s, 16);
    return r;
}

// ---------------- LN1 stats only: mu, rstd per row (row = 768) ----------------
__global__ __launch_bounds__(256) void k_ln_stats(const float* __restrict__ x,
                                                  float* __restrict__ mu, float* __restrict__ rs) {
    int row = blockIdx.x;
    int t = threadIdx.x;
    const float* xr = x + (size_t)row * E_;
    float v0 = xr[t], v1 = xr[t + 256], v2 = xr[t + 512];
    float s = v0 + v1 + v2;
    float ss = v0 * v0 + v1 * v1 + v2 * v2;
    for (int off = 32; off > 0; off >>= 1) {
        s  += __shfl_xor(s, off);
        ss += __shfl_xor(ss, off);
    }
    __shared__ float ls[4], lss[4];
    int w = t >> 6, l = t & 63;
    if (l == 0) { ls[w] = s; lss[w] = ss; }
    __syncthreads();
    if (t == 0) {
        s  = ls[0] + ls[1] + ls[2] + ls[3];
        ss = lss[0] + lss[1] + lss[2] + lss[3];
        float m = s * (1.0f / E_);
        float var = ss * (1.0f / E_) - m * m;
        mu[row] = m;
        rs[row] = rsqrtf(var + 1e-5f);
    }
}

// ---------------- full LayerNorm (ln2) -> bf16 ----------------
__global__ __launch_bounds__(256) void k_ln2(const float* __restrict__ x,
                                             const float* __restrict__ g,
                                             const float* __restrict__ b,
                                             bf16* __restrict__ out) {
    int row = blockIdx.x;
    int t = threadIdx.x;
    const float* xr = x + (size_t)row * E_;
    float v0 = xr[t], v1 = xr[t + 256], v2 = xr[t + 512];
    float s = v0 + v1 + v2;
    float ss = v0 * v0 + v1 * v1 + v2 * v2;
    for (int off = 32; off > 0; off >>= 1) {
        s  += __shfl_xor(s, off);
        ss += __shfl_xor(ss, off);
    }
    __shared__ float ls[4], lss[4];
    int w = t >> 6, l = t & 63;
    if (l == 0) { ls[w] = s; lss[w] = ss; }
    __syncthreads();
    s  = ls[0] + ls[1] + ls[2] + ls[3];
    ss = lss[0] + lss[1] + lss[2] + lss[3];
    float m = s * (1.0f / E_);
    float var = ss * (1.0f / E_) - m * m;
    float r = rsqrtf(var + 1e-5f);
    #pragma unroll
    for (int q = 0; q < 3; q++) {
        int e = t + q * 256;
        float v = (q == 0) ? v0 : ((q == 1) ? v1 : v2);
        out[(size_t)row * E_ + e] = (bf16)((v - m) * r * g[e] + b[e]);
    }
}

// ---------------- forward DFT along y (12 modes), LN1 fused on the fly ----------------
__global__ __launch_bounds__(256) void k_dft_y(const float* __restrict__ inp,
                                               const float* __restrict__ mu, const float* __restrict__ rs,
                                               const float* __restrict__ g, const float* __restrict__ bb,
                                               float* __restrict__ gre, float* __restrict__ gim) {
    int bid = blockIdx.x;                 // BT_*32*3
    int ec = bid % 3, x = (bid / 3) % 32, bt = bid / 96;
    int t = threadIdx.x;
    __shared__ float tile[32 * 256];
    __shared__ float c32[32], s32[32];
    if (t < 32) { float a = 6.28318530717958647692f * t / 32.0f; c32[t] = cosf(a); s32[t] = sinf(a); }
    int e = ec * 256 + t;
    float gv = g[e], bv = bb[e];
    int row0 = bt * S_ + x * 32;
    const float* base = inp + (size_t)row0 * E_ + e;
    for (int y = 0; y < 32; y++) {
        float m = mu[row0 + y], r = rs[row0 + y];
        tile[y * 256 + t] = (base[(size_t)y * E_] - m) * r * gv + bv;
    }
    __syncthreads();
    for (int ky = 0; ky < KM_; ky++) {
        float re = 0.f, im = 0.f;
        for (int y = 0; y < 32; y++) {
            int j = (ky * y) & 31;
            float v = tile[y * 256 + t];
            re += v * c32[j];
            im -= v * s32[j];
        }
        size_t o = ((size_t)((bt * 32 + x) * KM_ + ky)) * E_ + e;
        gre[o] = re; gim[o] = im;
    }
}

// ---------------- forward DFT along x (kx=5..28), scale 1/32; 32 KB LDS, 2-stage ----------------
__global__ __launch_bounds__(256) void k_dft_x(const float* __restrict__ gre, const float* __restrict__ gim,
                                               float* __restrict__ fr, float* __restrict__ fi) {
    int bid = blockIdx.x;                 // BT_*KM_*3
    int ec = bid % 3, ky = (bid / 3) % KM_, bt = bid / (3 * KM_);
    int t = threadIdx.x;
    __shared__ float lre[16 * 256];
    __shared__ float lim[16 * 256];
    __shared__ float c32[32], s32[32];
    if (t < 32) { float a = 6.28318530717958647692f * t / 32.0f; c32[t] = cosf(a); s32[t] = sinf(a); }
    float ar[KX_], ai[KX_];
    #pragma unroll
    for (int k = 0; k < KX_; k++) { ar[k] = 0.f; ai[k] = 0.f; }
    for (int half = 0; half < 2; half++) {
        __syncthreads();
        for (int xi = 0; xi < 16; xi++) {
            int x = half * 16 + xi;
            size_t o = ((size_t)((bt * 32 + x) * KM_ + ky)) * E_ + ec * 256 + t;
            lre[xi * 256 + t] = gre[o];
            lim[xi * 256 + t] = gim[o];
        }
        __syncthreads();
        for (int kxi = 0; kxi < KX_; kxi++) {
            int kx = kxi + 5;
            float re = 0.f, im = 0.f;
            #pragma unroll
            for (int xi = 0; xi < 16; xi++) {
                int j = (kx * (half * 16 + xi)) & 31;
                float c = c32[j], s = s32[j];
                float gr = lre[xi * 256 + t], gi = lim[xi * 256 + t];
                re += gr * c + gi * s;          // (gr+i*gi)*(c - i*s)
                im += gi * c - gr * s;
            }
            ar[kxi] += re; ai[kxi] += im;
        }
    }
    #pragma unroll
    for (int kxi = 0; kxi < KX_; kxi++) {
        size_t p = (size_t)(bt * KX_ + kxi) * KM_ + ky;
        fr[p * E_ + ec * 256 + t] = ar[kxi] * (1.0f / 32.0f);
        fi[p * E_ + ec * 256 + t] = ai[kxi] * (1.0f / 32.0f);
    }
}

// ---------------- MFMA block-diagonal complex 2-layer MLP + softshrink (in-place fr/fi) ----------------
// grid = NB_ * 36; each workgroup: one weight block n, 128 positions.
// LDS: X/O1 (reused) [128][72] bf16 r+i, 4 weight mats transposed [o][i] [64][72] bf16.
// Each wave owns 32 positions (rows wave*32..+31) -> no cross-wave hazards after staging barrier.
__global__ __launch_bounds__(256) void k_blockmlp(float* fr, float* fi,
                                                  const float* __restrict__ w1, const float* __restrict__ b1,
                                                  const float* __restrict__ w2, const float* __restrict__ b2) {
    int n = blockIdx.x / 36;
    int p0 = (blockIdx.x % 36) * 128;
    int t = threadIdx.x;
    __shared__ __align__(16) bf16 lXr[128 * 72];
    __shared__ __align__(16) bf16 lXi[128 * 72];
    __shared__ __align__(16) bf16 lW1a[64 * 72];
    __shared__ __align__(16) bf16 lW1b[64 * 72];
    __shared__ __align__(16) bf16 lW2a[64 * 72];
    __shared__ __align__(16) bf16 lW2b[64 * 72];

    // --- stage weights transposed ([o][i]), bf16 ---
    {
        int o = t & 63, iq = t >> 6;
        const float* s1a = w1 + (size_t)n * 4096;
        const float* s1b = w1 + (size_t)(NB_ + n) * 4096;
        const float* s2a = w2 + (size_t)n * 4096;
        const float* s2b = w2 + (size_t)(NB_ + n) * 4096;
        #pragma unroll
        for (int ii = 0; ii < 16; ii++) {
            int i = iq * 16 + ii;
            lW1a[o * 72 + i] = (bf16)s1a[i * 64 + o];
            lW1b[o * 72 + i] = (bf16)s1b[i * 64 + o];
            lW2a[o * 72 + i] = (bf16)s2a[i * 64 + o];
            lW2b[o * 72 + i] = (bf16)s2b[i * 64 + o];
        }
    }
    // --- stage X (fp32 -> bf16), rows = positions, stride 72 ---
    {
        int ch4 = (t & 15) * 4, prow = t >> 4;
        #pragma unroll
        for (int rep = 0; rep < 8; rep++) {
            int p = rep * 16 + prow;
            size_t ga = (size_t)(p0 + p) * E_ + n * 64 + ch4;
            float4 vr = *(const float4*)&fr[ga];
            float4 vi = *(const float4*)&fi[ga];
            bf16 br[4] = {(bf16)vr.x, (bf16)vr.y, (bf16)vr.z, (bf16)vr.w};
            bf16 bi[4] = {(bf16)vi.x, (bf16)vi.y, (bf16)vi.z, (bf16)vi.w};
            *(uint2*)&lXr[p * 72 + ch4] = *(uint2*)br;
            *(uint2*)&lXi[p * 72 + ch4] = *(uint2*)bi;
        }
    }
    int w = t >> 6, l = t & 63, lr = l & 15, lq = l >> 4;
    // per-lane biases (channel o = ni*16+lr)
    float bias1r[4], bias1i[4], bias2r[4], bias2i[4];
    #pragma unroll
    for (int ni = 0; ni < 4; ni++) {
        int o = n * 64 + ni * 16 + lr;
        bias1r[ni] = b1[o]; bias1i[ni] = b1[NB_ * 64 + o];
        bias2r[ni] = b2[o]; bias2i[ni] = b2[NB_ * 64 + o];
    }
    __syncthreads();

    // --- layer 1: rows w*32 + mt*16, N=64, K=64 ---
    f32x4 a1r[2][4], a1i[2][4];
    #pragma unroll
    for (int mt = 0; mt < 2; mt++)
        #pragma unroll
        for (int ni = 0; ni < 4; ni++) { a1r[mt][ni] = (f32x4){0,0,0,0}; a1i[mt][ni] = (f32x4){0,0,0,0}; }
    #pragma unroll
    for (int ks = 0; ks < 2; ks++) {
        int k0 = ks * 32;
        bf16x8 xr[2], xi[2], xin[2];
        #pragma unroll
        for (int mt = 0; mt < 2; mt++) {
            int row = w * 32 + mt * 16 + lr;
            xr[mt]  = *(bf16x8*)&lXr[row * 72 + k0 + lq * 8];
            xi[mt]  = *(bf16x8*)&lXi[row * 72 + k0 + lq * 8];
            xin[mt] = neg8(xi[mt]);
        }
        #pragma unroll
        for (int ni = 0; ni < 4; ni++) {
            bf16x8 ba = *(bf16x8*)&lW1a[(ni * 16 + lr) * 72 + k0 + lq * 8];
            bf16x8 bb = *(bf16x8*)&lW1b[(ni * 16 + lr) * 72 + k0 + lq * 8];
            #pragma unroll
            for (int mt = 0; mt < 2; mt++) {
                a1r[mt][ni] = __builtin_amdgcn_mfma_f32_16x16x32_bf16(xr[mt],  ba, a1r[mt][ni], 0, 0, 0);
                a1r[mt][ni] = __builtin_amdgcn_mfma_f32_16x16x32_bf16(xin[mt], bb, a1r[mt][ni], 0, 0, 0);
                a1i[mt][ni] = __builtin_amdgcn_mfma_f32_16x16x32_bf16(xi[mt],  ba, a1i[mt][ni], 0, 0, 0);
                a1i[mt][ni] = __builtin_amdgcn_mfma_f32_16x16x32_bf16(xr[mt],  bb, a1i[mt][ni], 0, 0, 0);
            }
        }
    }
    // bias + gelu, write O1 back into lXr/lXi (own rows only -> no barrier needed)
    #pragma unroll
    for (int mt = 0; mt < 2; mt++)
        #pragma unroll
        for (int ni = 0; ni < 4; ni++) {
            int o = ni * 16 + lr;
            #pragma unroll
            for (int r = 0; r < 4; r++) {
                int row = w * 32 + mt * 16 + lq * 4 + r;
                lXr[row * 72 + o] = (bf16)gelu_exact(a1r[mt][ni][r] + bias1r[ni]);
                lXi[row * 72 + o] = (bf16)gelu_exact(a1i[mt][ni][r] + bias1i[ni]);
            }
        }

    // --- layer 2 ---
    f32x4 a2r[2][4], a2i[2][4];
    #pragma unroll
    for (int mt = 0; mt < 2; mt++)
        #pragma unroll
        for (int ni = 0; ni < 4; ni++) { a2r[mt][ni] = (f32x4){0,0,0,0}; a2i[mt][ni] = (f32x4){0,0,0,0}; }
    #pragma unroll
    for (int ks = 0; ks < 2; ks++) {
        int k0 = ks * 32;
        bf16x8 xr[2], xi[2], xin[2];
        #pragma unroll
        for (int mt = 0; mt < 2; mt++) {
            int row = w * 32 + mt * 16 + lr;
            xr[mt]  = *(bf16x8*)&lXr[row * 72 + k0 + lq * 8];
            xi[mt]  = *(bf16x8*)&lXi[row * 72 + k0 + lq * 8];
            xin[mt] = neg8(xi[mt]);
        }
        #pragma unroll
        for (int ni = 0; ni < 4; ni++) {
            bf16x8 ba = *(bf16x8*)&lW2a[(ni * 16 + lr) * 72 + k0 + lq * 8];
            bf16x8 bb = *(bf16x8*)&lW2b[(ni * 16 + lr) * 72 + k0 + lq * 8];
            #pragma unroll
            for (int mt = 0; mt < 2; mt++) {
                a2r[mt][ni] = __builtin_amdgcn_mfma_f32_16x16x32_bf16(xr[mt],  ba, a2r[mt][ni], 0, 0, 0);
                a2r[mt][ni] = __builtin_amdgcn_mfma_f32_16x16x32_bf16(xin[mt], bb, a2r[mt][ni], 0, 0, 0);
                a2i[mt][ni] = __builtin_amdgcn_mfma_f32_16x16x32_bf16(xi[mt],  ba, a2i[mt][ni], 0, 0, 0);
                a2i[mt][ni] = __builtin_amdgcn_mfma_f32_16x16x32_bf16(xr[mt],  bb, a2i[mt][ni], 0, 0, 0);
            }
        }
    }
    // bias + softshrink, write back to fr/fi
    #pragma unroll
    for (int mt = 0; mt < 2; mt++)
        #pragma unroll
        for (int ni = 0; ni < 4; ni++) {
            int o = ni * 16 + lr;
            #pragma unroll
            for (int r = 0; r < 4; r++) {
                int row = w * 32 + mt * 16 + lq * 4 + r;
                float vr = a2r[mt][ni][r] + bias2r[ni];
                float vi = a2i[mt][ni][r] + bias2i[ni];
                vr = (vr > 0.01f) ? vr - 0.01f : ((vr < -0.01f) ? vr + 0.01f : 0.0f);
                vi = (vi > 0.01f) ? vi - 0.01f : ((vi < -0.01f) ? vi + 0.01f : 0.0f);
                size_t ga = (size_t)(p0 + row) * E_ + n * 64 + o;
                fr[ga] = vr;
                fi[ga] = vi;
            }
        }
}

// ---------------- inverse DFT along x (complex ifft, 24 input modes) ----------------
__global__ __launch_bounds__(256) void k_idft_x(const float* __restrict__ pr_, const float* __restrict__ pi_,
                                                float* __restrict__ zre, float* __restrict__ zim) {
    int bid = blockIdx.x;                 // BT_*KM_*3
    int ec = bid % 3, ky = (bid / 3) % KM_, bt = bid / (3 * KM_);
    int t = threadIdx.x;
    __shared__ float lre[KX_ * 256], lim[KX_ * 256];
    __shared__ float c32[32], s32[32];
    if (t < 32) { float a = 6.28318530717958647692f * t / 32.0f; c32[t] = cosf(a); s32[t] = sinf(a); }
    for (int kxi = 0; kxi < KX_; kxi++) {
        size_t p = (size_t)(bt * KX_ + kxi) * KM_ + ky;
        lre[kxi * 256 + t] = pr_[p * E_ + ec * 256 + t];
        lim[kxi * 256 + t] = pi_[p * E_ + ec * 256 + t];
    }
    __syncthreads();
    for (int x = 0; x < 32; x++) {
        float re = 0.f, im = 0.f;
        for (int kxi = 0; kxi < KX_; kxi++) {
            int kx = kxi + 5;
            int j = (kx * x) & 31;
            float c = c32[j], s = s32[j];
            float pr = lre[kxi * 256 + t], pi = lim[kxi * 256 + t];
            re += pr * c - pi * s;          // (pr+i*pi)*(c + i*s)
            im += pr * s + pi * c;
        }
        size_t zo = ((size_t)((bt * 32 + x) * KM_ + ky)) * E_ + ec * 256 + t;
        zre[zo] = re; zim[zo] = im;
    }
}

// ---------------- inverse rfft along y + residuals: out = spat + ln1(inp) + inp ----------------
__global__ __launch_bounds__(256) void k_idft_y_res(const float* __restrict__ zre, const float* __restrict__ zim,
                                                    const float* __restrict__ inp,
                                                    const float* __restrict__ mu, const float* __restrict__ rs,
                                                    const float* __restrict__ g, const float* __restrict__ bb,
                                                    float* __restrict__ out) {
    int bid = blockIdx.x;                 // BT_*32*3
    int ec = bid % 3, x = (bid / 3) % 32, bt = bid / 96;
    int t = threadIdx.x;
    __shared__ float lre[KM_ * 256], lim[KM_ * 256];
    __shared__ float c32[32], s32[32];
    if (t < 32) { float a = 6.28318530717958647692f * t / 32.0f; c32[t] = cosf(a); s32[t] = sinf(a); }
    for (int ky = 0; ky < KM_; ky++) {
        size_t zo = ((size_t)((bt * 32 + x) * KM_ + ky)) * E_ + ec * 256 + t;
        lre[ky * 256 + t] = zre[zo];
        lim[ky * 256 + t] = zim[zo];
    }
    __syncthreads();
    int e = ec * 256 + t;
    float gv = g[e], bv = bb[e];
    int row0 = bt * S_ + x * 32;
    for (int y = 0; y < 32; y++) {
        float v = lre[t];                 // ky=0: Re only (irfft drops Im of DC)
        for (int ky = 1; ky < KM_; ky++) {
            int j = (ky * y) & 31;
            v += 2.0f * (lre[ky * 256 + t] * c32[j] - lim[ky * 256 + t] * s32[j]);
        }
        v *= (1.0f / 32.0f);
        size_t o = (size_t)(row0 + y) * E_ + e;
        float iv = inp[o];
        float m = mu[row0 + y], r = rs[row0 + y];
        out[o] = v + ((iv - m) * r * gv + bv) + iv;
    }
}

// ---------------- fp32 [R][C] -> bf16 [C][R] transpose+cast ----------------
__global__ void k_transpose_cast(const float* __restrict__ src, bf16* __restrict__ dst, int R, int C) {
    __shared__ float tile[32][33];
    int c0 = blockIdx.x * 32, r0 = blockIdx.y * 32;
    int tx = threadIdx.x, ty = threadIdx.y;
    #pragma unroll
    for (int j = 0; j < 32; j += 8)
        tile[ty + j][tx] = src[(size_t)(r0 + ty + j) * C + c0 + tx];
    __syncthreads();
    #pragma unroll
    for (int j = 0; j < 32; j += 8)
        dst[(size_t)(c0 + ty + j) * R + r0 + tx] = (bf16)tile[tx][ty + j];
}

// ---------------- bf16 MFMA GEMM, 128x128 tile, BK=32, async global->LDS staging ----------------
template<bool FUSE_GELU>
__global__ __launch_bounds__(256) void k_gemm(const bf16* __restrict__ A, const bf16* __restrict__ Bt,
                                              const float* __restrict__ bias, int M, int N, int K,
                                              bf16* __restrict__ outb, float* __restrict__ outf) {
    __shared__ __align__(16) bf16 lA[128 * 32];
    __shared__ __align__(16) bf16 lB[128 * 32];
    int t = threadIdx.x;
    int m0 = blockIdx.x * 128, n0 = blockIdx.y * 128;
    int w = t >> 6, l = t & 63;
    int wm = (w & 1) * 64, wn = (w >> 1) * 64;
    int lr = l & 15, lq = l >> 4;
    f32x4 acc[4][4];
    #pragma unroll
    for (int i = 0; i < 4; i++)
        #pragma unroll
        for (int j = 0; j < 4; j++)
            acc[i][j] = (f32x4){0.f, 0.f, 0.f, 0.f};
    const bf16* gA = A + (size_t)m0 * K;
    const bf16* gB = Bt + (size_t)n0 * K;
    int nk = K / 32;
    for (int kt = 0; kt < nk; kt++) {
        const bf16* pa = gA + kt * 32;
        const bf16* pb = gB + kt * 32;
        #pragma unroll
        for (int q = 0; q < 2; q++) {
            int cid = q * 256 + t;
            int row = cid >> 2, ks = cid & 3;
            bf16* ldsbase = (bf16*)((char*)0 + 0);  // placate nothing
            (void)ldsbase;
            gload16(pa + (size_t)row * K + ks * 8, &lA[(q * 256 + (t & ~63)) * 8]);
            gload16(pb + (size_t)row * K + ks * 8, &lB[(q * 256 + (t & ~63)) * 8]);
        }
        __syncthreads();
        bf16x8 af[4], bfv[4];
        #pragma unroll
        for (int mi = 0; mi < 4; mi++) af[mi]  = *(bf16x8*)&lA[(wm + mi * 16 + lr) * 32 + lq * 8];
        #pragma unroll
        for (int ni = 0; ni < 4; ni++) bfv[ni] = *(bf16x8*)&lB[(wn + ni * 16 + lr) * 32 + lq * 8];
        #pragma unroll
        for (int mi = 0; mi < 4; mi++)
            #pragma unroll
            for (int ni = 0; ni < 4; ni++)
                acc[mi][ni] = __builtin_amdgcn_mfma_f32_16x16x32_bf16(af[mi], bfv[ni], acc[mi][ni], 0, 0, 0);
        __syncthreads();
    }
    #pragma unroll
    for (int mi = 0; mi < 4; mi++) {
        #pragma unroll
        for (int ni = 0; ni < 4; ni++) {
            int col = n0 + wn + ni * 16 + lr;
            float bv = bias[col];
            #pragma unroll
            for (int r = 0; r < 4; r++) {
                int row = m0 + wm + mi * 16 + lq * 4 + r;
                float v = acc[mi][ni][r] + bv;
                if (FUSE_GELU) {
                    outb[(size_t)row * N + col] = (bf16)gelu_exact(v);
                } else {
                    size_t oo = (size_t)row * N + col;
                    outf[oo] = v + outf[oo];
                }
            }
        }
    }
}

extern "C" void kernel_launch(void* const* d_in, const int* in_sizes, int n_in,
                              void* d_out, int out_size, void* d_ws, size_t ws_size,
                              hipStream_t stream) {
    const float* input = (const float*)d_in[0];
    const float* w1    = (const float*)d_in[1];
    const float* b1    = (const float*)d_in[2];
    const float* w2    = (const float*)d_in[3];
    const float* b2    = (const float*)d_in[4];
    const float* ln1g  = (const float*)d_in[5];
    const float* ln1b  = (const float*)d_in[6];
    const float* ln2g  = (const float*)d_in[7];
    const float* ln2b  = (const float*)d_in[8];
    const float* mw1   = (const float*)d_in[9];
    const float* mb1   = (const float*)d_in[10];
    const float* mw2   = (const float*)d_in[11];
    const float* mb2   = (const float*)d_in[12];
    float* out = (float*)d_out;

    // ---- workspace: total 16,547,840 floats = 66.2 MB ----
    float* ws = (float*)d_ws;
    float* mu  = ws;                       // 16384
    float* rs  = ws + 16384;               // 16384
    const size_t BASE = 32768;
    float* gre = ws + BASE;                // 4,718,592
    float* gim = gre + 4718592;            // 4,718,592
    float* fr  = ws + BASE + 2 * 4718592;  // 3,538,944
    float* fi  = fr + 3538944;             // 3,538,944
    bf16* lnA = (bf16*)(ws + BASE);                  // 12,582,912 bf16
    bf16* w1T = (bf16*)(ws + BASE + 6291456);        //  2,359,296 bf16
    bf16* w2T = (bf16*)(ws + BASE + 7471104);        //  2,359,296 bf16
    bf16* mid = (bf16*)(ws + BASE + 8650752);        // 12,582,912 bf16 (4096x3072)

    k_ln_stats<<<16384, 256, 0, stream>>>(input, mu, rs);
    k_dft_y<<<BT_ * 32 * 3, 256, 0, stream>>>(input, mu, rs, ln1g, ln1b, gre, gim);
    k_dft_x<<<BT_ * KM_ * 3, 256, 0, stream>>>(gre, gim, fr, fi);
    k_blockmlp<<<NB_ * 36, 256, 0, stream>>>(fr, fi, w1, b1, w2, b2);
    k_idft_x<<<BT_ * KM_ * 3, 256, 0, stream>>>(fr, fi, gre, gim);   // gre/gim now hold Z
    k_idft_y_res<<<BT_ * 32 * 3, 256, 0, stream>>>(gre, gim, input, mu, rs, ln1g, ln1b, out);
    k_ln2<<<16384, 256, 0, stream>>>(out, ln2g, ln2b, lnA);
    k_transpose_cast<<<dim3(3072 / 32, 768 / 32), dim3(32, 8), 0, stream>>>(mw1, w1T, 768, 3072);
    k_transpose_cast<<<dim3(768 / 32, 3072 / 32), dim3(32, 8), 0, stream>>>(mw2, w2T, 3072, 768);
    for (int c = 0; c < 4; c++) {
        const bf16* aC = lnA + (size_t)c * 4096 * 768;
        float* oC = out + (size_t)c * 4096 * 768;
        k_gemm<true><<<dim3(32, 24), 256, 0, stream>>>(aC, w1T, mb1, 4096, 3072, 768, mid, nullptr);
        k_gemm<false><<<dim3(32, 6), 256, 0, stream>>>(mid, w2T, mb2, 4096, 768, 3072, nullptr, oC);
    }
}

// Round 4
// 542.747 us; speedup vs baseline: 1.7807x; 1.4429x over previous
//
#include <hip/hip_runtime.h>
#include <hip/hip_bf16.h>
#include <math.h>

typedef __bf16 bf16;
typedef __bf16 bf16x8 __attribute__((ext_vector_type(8)));
typedef float f32x4 __attribute__((ext_vector_type(4)));
typedef short short8 __attribute__((ext_vector_type(8)));

#define E_ 768
#define S_ 1024
#define BT_ 16
#define KM_ 12
#define KX_ 24
#define NPOS_ 4608
#define NB_ 12
#define LDST 40   // LDS row stride (bf16 elems): 80B -> 16B-aligned, conflict-free

__device__ __forceinline__ float gelu_exact(float x) {
    return 0.5f * x * (1.0f + erff(x * 0.70710678118654752f));
}

// negate 8 bf16 lanes (flip sign bits) — MFMA has no subtract-accumulate
__device__ __forceinline__ bf16x8 neg8(bf16x8 v) {
    short8 s;
    __builtin_memcpy(&s, &v, 16);
    s ^= (short)0x8000;
    bf16x8 r;
    __builtin_memcpy(&r, &s, 16);
    return r;
}

// ---------------- LN1 stats only: mu, rstd per row (row = 768) ----------------
__global__ __launch_bounds__(256) void k_ln_stats(const float* __restrict__ x,
                                                  float* __restrict__ mu, float* __restrict__ rs) {
    int row = blockIdx.x;
    int t = threadIdx.x;
    const float* xr = x + (size_t)row * E_;
    float v0 = xr[t], v1 = xr[t + 256], v2 = xr[t + 512];
    float s = v0 + v1 + v2;
    float ss = v0 * v0 + v1 * v1 + v2 * v2;
    for (int off = 32; off > 0; off >>= 1) {
        s  += __shfl_xor(s, off);
        ss += __shfl_xor(ss, off);
    }
    __shared__ float ls[4], lss[4];
    int w = t >> 6, l = t & 63;
    if (l == 0) { ls[w] = s; lss[w] = ss; }
    __syncthreads();
    if (t == 0) {
        s  = ls[0] + ls[1] + ls[2] + ls[3];
        ss = lss[0] + lss[1] + lss[2] + lss[3];
        float m = s * (1.0f / E_);
        float var = ss * (1.0f / E_) - m * m;
        mu[row] = m;
        rs[row] = rsqrtf(var + 1e-5f);
    }
}

// ---------------- full LayerNorm (ln2) -> bf16 ----------------
__global__ __launch_bounds__(256) void k_ln2(const float* __restrict__ x,
                                             const float* __restrict__ g,
                                             const float* __restrict__ b,
                                             bf16* __restrict__ out) {
    int row = blockIdx.x;
    int t = threadIdx.x;
    const float* xr = x + (size_t)row * E_;
    float v0 = xr[t], v1 = xr[t + 256], v2 = xr[t + 512];
    float s = v0 + v1 + v2;
    float ss = v0 * v0 + v1 * v1 + v2 * v2;
    for (int off = 32; off > 0; off >>= 1) {
        s  += __shfl_xor(s, off);
        ss += __shfl_xor(ss, off);
    }
    __shared__ float ls[4], lss[4];
    int w = t >> 6, l = t & 63;
    if (l == 0) { ls[w] = s; lss[w] = ss; }
    __syncthreads();
    s  = ls[0] + ls[1] + ls[2] + ls[3];
    ss = lss[0] + lss[1] + lss[2] + lss[3];
    float m = s * (1.0f / E_);
    float var = ss * (1.0f / E_) - m * m;
    float r = rsqrtf(var + 1e-5f);
    #pragma unroll
    for (int q = 0; q < 3; q++) {
        int e = t + q * 256;
        float v = (q == 0) ? v0 : ((q == 1) ? v1 : v2);
        out[(size_t)row * E_ + e] = (bf16)((v - m) * r * g[e] + b[e]);
    }
}

// ---------------- forward DFT along y (12 modes), LN1 fused on the fly ----------------
__global__ __launch_bounds__(256) void k_dft_y(const float* __restrict__ inp,
                                               const float* __restrict__ mu, const float* __restrict__ rs,
                                               const float* __restrict__ g, const float* __restrict__ bb,
                                               float* __restrict__ gre, float* __restrict__ gim) {
    int bid = blockIdx.x;                 // BT_*32*3
    int ec = bid % 3, x = (bid / 3) % 32, bt = bid / 96;
    int t = threadIdx.x;
    __shared__ float tile[32 * 256];
    __shared__ float c32[32], s32[32];
    if (t < 32) { float a = 6.28318530717958647692f * t / 32.0f; c32[t] = cosf(a); s32[t] = sinf(a); }
    int e = ec * 256 + t;
    float gv = g[e], bv = bb[e];
    int row0 = bt * S_ + x * 32;
    const float* base = inp + (size_t)row0 * E_ + e;
    for (int y = 0; y < 32; y++) {
        float m = mu[row0 + y], r = rs[row0 + y];
        tile[y * 256 + t] = (base[(size_t)y * E_] - m) * r * gv + bv;
    }
    __syncthreads();
    for (int ky = 0; ky < KM_; ky++) {
        float re = 0.f, im = 0.f;
        for (int y = 0; y < 32; y++) {
            int j = (ky * y) & 31;
            float v = tile[y * 256 + t];
            re += v * c32[j];
            im -= v * s32[j];
        }
        size_t o = ((size_t)((bt * 32 + x) * KM_ + ky)) * E_ + e;
        gre[o] = re; gim[o] = im;
    }
}

// ---------------- forward DFT along x (kx=5..28), scale 1/32; 32 KB LDS, 2-stage ----------------
__global__ __launch_bounds__(256) void k_dft_x(const float* __restrict__ gre, const float* __restrict__ gim,
                                               float* __restrict__ fr, float* __restrict__ fi) {
    int bid = blockIdx.x;                 // BT_*KM_*3
    int ec = bid % 3, ky = (bid / 3) % KM_, bt = bid / (3 * KM_);
    int t = threadIdx.x;
    __shared__ float lre[16 * 256];
    __shared__ float lim[16 * 256];
    __shared__ float c32[32], s32[32];
    if (t < 32) { float a = 6.28318530717958647692f * t / 32.0f; c32[t] = cosf(a); s32[t] = sinf(a); }
    float ar[KX_], ai[KX_];
    #pragma unroll
    for (int k = 0; k < KX_; k++) { ar[k] = 0.f; ai[k] = 0.f; }
    for (int half = 0; half < 2; half++) {
        __syncthreads();
        for (int xi = 0; xi < 16; xi++) {
            int x = half * 16 + xi;
            size_t o = ((size_t)((bt * 32 + x) * KM_ + ky)) * E_ + ec * 256 + t;
            lre[xi * 256 + t] = gre[o];
            lim[xi * 256 + t] = gim[o];
        }
        __syncthreads();
        for (int kxi = 0; kxi < KX_; kxi++) {
            int kx = kxi + 5;
            float re = 0.f, im = 0.f;
            #pragma unroll
            for (int xi = 0; xi < 16; xi++) {
                int j = (kx * (half * 16 + xi)) & 31;
                float c = c32[j], s = s32[j];
                float gr = lre[xi * 256 + t], gi = lim[xi * 256 + t];
                re += gr * c + gi * s;          // (gr+i*gi)*(c - i*s)
                im += gi * c - gr * s;
            }
            ar[kxi] += re; ai[kxi] += im;
        }
    }
    #pragma unroll
    for (int kxi = 0; kxi < KX_; kxi++) {
        size_t p = (size_t)(bt * KX_ + kxi) * KM_ + ky;
        fr[p * E_ + ec * 256 + t] = ar[kxi] * (1.0f / 32.0f);
        fi[p * E_ + ec * 256 + t] = ai[kxi] * (1.0f / 32.0f);
    }
}

// ---------------- MFMA block-diagonal complex 2-layer MLP + softshrink (in-place fr/fi) ----------------
__global__ __launch_bounds__(256) void k_blockmlp(float* fr, float* fi,
                                                  const float* __restrict__ w1, const float* __restrict__ b1,
                                                  const float* __restrict__ w2, const float* __restrict__ b2) {
    int n = blockIdx.x / 36;
    int p0 = (blockIdx.x % 36) * 128;
    int t = threadIdx.x;
    __shared__ __align__(16) bf16 lXr[128 * 72];
    __shared__ __align__(16) bf16 lXi[128 * 72];
    __shared__ __align__(16) bf16 lW1a[64 * 72];
    __shared__ __align__(16) bf16 lW1b[64 * 72];
    __shared__ __align__(16) bf16 lW2a[64 * 72];
    __shared__ __align__(16) bf16 lW2b[64 * 72];

    {
        int o = t & 63, iq = t >> 6;
        const float* s1a = w1 + (size_t)n * 4096;
        const float* s1b = w1 + (size_t)(NB_ + n) * 4096;
        const float* s2a = w2 + (size_t)n * 4096;
        const float* s2b = w2 + (size_t)(NB_ + n) * 4096;
        #pragma unroll
        for (int ii = 0; ii < 16; ii++) {
            int i = iq * 16 + ii;
            lW1a[o * 72 + i] = (bf16)s1a[i * 64 + o];
            lW1b[o * 72 + i] = (bf16)s1b[i * 64 + o];
            lW2a[o * 72 + i] = (bf16)s2a[i * 64 + o];
            lW2b[o * 72 + i] = (bf16)s2b[i * 64 + o];
        }
    }
    {
        int ch4 = (t & 15) * 4, prow = t >> 4;
        #pragma unroll
        for (int rep = 0; rep < 8; rep++) {
            int p = rep * 16 + prow;
            size_t ga = (size_t)(p0 + p) * E_ + n * 64 + ch4;
            float4 vr = *(const float4*)&fr[ga];
            float4 vi = *(const float4*)&fi[ga];
            bf16 br[4] = {(bf16)vr.x, (bf16)vr.y, (bf16)vr.z, (bf16)vr.w};
            bf16 bi[4] = {(bf16)vi.x, (bf16)vi.y, (bf16)vi.z, (bf16)vi.w};
            *(uint2*)&lXr[p * 72 + ch4] = *(uint2*)br;
            *(uint2*)&lXi[p * 72 + ch4] = *(uint2*)bi;
        }
    }
    int w = t >> 6, l = t & 63, lr = l & 15, lq = l >> 4;
    float bias1r[4], bias1i[4], bias2r[4], bias2i[4];
    #pragma unroll
    for (int ni = 0; ni < 4; ni++) {
        int o = n * 64 + ni * 16 + lr;
        bias1r[ni] = b1[o]; bias1i[ni] = b1[NB_ * 64 + o];
        bias2r[ni] = b2[o]; bias2i[ni] = b2[NB_ * 64 + o];
    }
    __syncthreads();

    f32x4 a1r[2][4], a1i[2][4];
    #pragma unroll
    for (int mt = 0; mt < 2; mt++)
        #pragma unroll
        for (int ni = 0; ni < 4; ni++) { a1r[mt][ni] = (f32x4){0,0,0,0}; a1i[mt][ni] = (f32x4){0,0,0,0}; }
    #pragma unroll
    for (int ks = 0; ks < 2; ks++) {
        int k0 = ks * 32;
        bf16x8 xr[2], xi[2], xin[2];
        #pragma unroll
        for (int mt = 0; mt < 2; mt++) {
            int row = w * 32 + mt * 16 + lr;
            xr[mt]  = *(bf16x8*)&lXr[row * 72 + k0 + lq * 8];
            xi[mt]  = *(bf16x8*)&lXi[row * 72 + k0 + lq * 8];
            xin[mt] = neg8(xi[mt]);
        }
        #pragma unroll
        for (int ni = 0; ni < 4; ni++) {
            bf16x8 ba = *(bf16x8*)&lW1a[(ni * 16 + lr) * 72 + k0 + lq * 8];
            bf16x8 bb = *(bf16x8*)&lW1b[(ni * 16 + lr) * 72 + k0 + lq * 8];
            #pragma unroll
            for (int mt = 0; mt < 2; mt++) {
                a1r[mt][ni] = __builtin_amdgcn_mfma_f32_16x16x32_bf16(xr[mt],  ba, a1r[mt][ni], 0, 0, 0);
                a1r[mt][ni] = __builtin_amdgcn_mfma_f32_16x16x32_bf16(xin[mt], bb, a1r[mt][ni], 0, 0, 0);
                a1i[mt][ni] = __builtin_amdgcn_mfma_f32_16x16x32_bf16(xi[mt],  ba, a1i[mt][ni], 0, 0, 0);
                a1i[mt][ni] = __builtin_amdgcn_mfma_f32_16x16x32_bf16(xr[mt],  bb, a1i[mt][ni], 0, 0, 0);
            }
        }
    }
    #pragma unroll
    for (int mt = 0; mt < 2; mt++)
        #pragma unroll
        for (int ni = 0; ni < 4; ni++) {
            int o = ni * 16 + lr;
            #pragma unroll
            for (int r = 0; r < 4; r++) {
                int row = w * 32 + mt * 16 + lq * 4 + r;
                lXr[row * 72 + o] = (bf16)gelu_exact(a1r[mt][ni][r] + bias1r[ni]);
                lXi[row * 72 + o] = (bf16)gelu_exact(a1i[mt][ni][r] + bias1i[ni]);
            }
        }

    f32x4 a2r[2][4], a2i[2][4];
    #pragma unroll
    for (int mt = 0; mt < 2; mt++)
        #pragma unroll
        for (int ni = 0; ni < 4; ni++) { a2r[mt][ni] = (f32x4){0,0,0,0}; a2i[mt][ni] = (f32x4){0,0,0,0}; }
    #pragma unroll
    for (int ks = 0; ks < 2; ks++) {
        int k0 = ks * 32;
        bf16x8 xr[2], xi[2], xin[2];
        #pragma unroll
        for (int mt = 0; mt < 2; mt++) {
            int row = w * 32 + mt * 16 + lr;
            xr[mt]  = *(bf16x8*)&lXr[row * 72 + k0 + lq * 8];
            xi[mt]  = *(bf16x8*)&lXi[row * 72 + k0 + lq * 8];
            xin[mt] = neg8(xi[mt]);
        }
        #pragma unroll
        for (int ni = 0; ni < 4; ni++) {
            bf16x8 ba = *(bf16x8*)&lW2a[(ni * 16 + lr) * 72 + k0 + lq * 8];
            bf16x8 bb = *(bf16x8*)&lW2b[(ni * 16 + lr) * 72 + k0 + lq * 8];
            #pragma unroll
            for (int mt = 0; mt < 2; mt++) {
                a2r[mt][ni] = __builtin_amdgcn_mfma_f32_16x16x32_bf16(xr[mt],  ba, a2r[mt][ni], 0, 0, 0);
                a2r[mt][ni] = __builtin_amdgcn_mfma_f32_16x16x32_bf16(xin[mt], bb, a2r[mt][ni], 0, 0, 0);
                a2i[mt][ni] = __builtin_amdgcn_mfma_f32_16x16x32_bf16(xi[mt],  ba, a2i[mt][ni], 0, 0, 0);
                a2i[mt][ni] = __builtin_amdgcn_mfma_f32_16x16x32_bf16(xr[mt],  bb, a2i[mt][ni], 0, 0, 0);
            }
        }
    }
    #pragma unroll
    for (int mt = 0; mt < 2; mt++)
        #pragma unroll
        for (int ni = 0; ni < 4; ni++) {
            int o = ni * 16 + lr;
            #pragma unroll
            for (int r = 0; r < 4; r++) {
                int row = w * 32 + mt * 16 + lq * 4 + r;
                float vr = a2r[mt][ni][r] + bias2r[ni];
                float vi = a2i[mt][ni][r] + bias2i[ni];
                vr = (vr > 0.01f) ? vr - 0.01f : ((vr < -0.01f) ? vr + 0.01f : 0.0f);
                vi = (vi > 0.01f) ? vi - 0.01f : ((vi < -0.01f) ? vi + 0.01f : 0.0f);
                size_t ga = (size_t)(p0 + row) * E_ + n * 64 + o;
                fr[ga] = vr;
                fi[ga] = vi;
            }
        }
}

// ---------------- inverse DFT along x (complex ifft, 24 input modes) ----------------
__global__ __launch_bounds__(256) void k_idft_x(const float* __restrict__ pr_, const float* __restrict__ pi_,
                                                float* __restrict__ zre, float* __restrict__ zim) {
    int bid = blockIdx.x;                 // BT_*KM_*3
    int ec = bid % 3, ky = (bid / 3) % KM_, bt = bid / (3 * KM_);
    int t = threadIdx.x;
    __shared__ float lre[KX_ * 256], lim[KX_ * 256];
    __shared__ float c32[32], s32[32];
    if (t < 32) { float a = 6.28318530717958647692f * t / 32.0f; c32[t] = cosf(a); s32[t] = sinf(a); }
    for (int kxi = 0; kxi < KX_; kxi++) {
        size_t p = (size_t)(bt * KX_ + kxi) * KM_ + ky;
        lre[kxi * 256 + t] = pr_[p * E_ + ec * 256 + t];
        lim[kxi * 256 + t] = pi_[p * E_ + ec * 256 + t];
    }
    __syncthreads();
    for (int x = 0; x < 32; x++) {
        float re = 0.f, im = 0.f;
        for (int kxi = 0; kxi < KX_; kxi++) {
            int kx = kxi + 5;
            int j = (kx * x) & 31;
            float c = c32[j], s = s32[j];
            float pr = lre[kxi * 256 + t], pi = lim[kxi * 256 + t];
            re += pr * c - pi * s;          // (pr+i*pi)*(c + i*s)
            im += pr * s + pi * c;
        }
        size_t zo = ((size_t)((bt * 32 + x) * KM_ + ky)) * E_ + ec * 256 + t;
        zre[zo] = re; zim[zo] = im;
    }
}

// ---------------- inverse rfft along y + residuals: out = spat + ln1(inp) + inp ----------------
__global__ __launch_bounds__(256) void k_idft_y_res(const float* __restrict__ zre, const float* __restrict__ zim,
                                                    const float* __restrict__ inp,
                                                    const float* __restrict__ mu, const float* __restrict__ rs,
                                                    const float* __restrict__ g, const float* __restrict__ bb,
                                                    float* __restrict__ out) {
    int bid = blockIdx.x;                 // BT_*32*3
    int ec = bid % 3, x = (bid / 3) % 32, bt = bid / 96;
    int t = threadIdx.x;
    __shared__ float lre[KM_ * 256], lim[KM_ * 256];
    __shared__ float c32[32], s32[32];
    if (t < 32) { float a = 6.28318530717958647692f * t / 32.0f; c32[t] = cosf(a); s32[t] = sinf(a); }
    for (int ky = 0; ky < KM_; ky++) {
        size_t zo = ((size_t)((bt * 32 + x) * KM_ + ky)) * E_ + ec * 256 + t;
        lre[ky * 256 + t] = zre[zo];
        lim[ky * 256 + t] = zim[zo];
    }
    __syncthreads();
    int e = ec * 256 + t;
    float gv = g[e], bv = bb[e];
    int row0 = bt * S_ + x * 32;
    for (int y = 0; y < 32; y++) {
        float v = lre[t];                 // ky=0: Re only (irfft drops Im of DC)
        for (int ky = 1; ky < KM_; ky++) {
            int j = (ky * y) & 31;
            v += 2.0f * (lre[ky * 256 + t] * c32[j] - lim[ky * 256 + t] * s32[j]);
        }
        v *= (1.0f / 32.0f);
        size_t o = (size_t)(row0 + y) * E_ + e;
        float iv = inp[o];
        float m = mu[row0 + y], r = rs[row0 + y];
        out[o] = v + ((iv - m) * r * gv + bv) + iv;
    }
}

// ---------------- fp32 [R][C] -> bf16 [C][R] transpose+cast ----------------
__global__ void k_transpose_cast(const float* __restrict__ src, bf16* __restrict__ dst, int R, int C) {
    __shared__ float tile[32][33];
    int c0 = blockIdx.x * 32, r0 = blockIdx.y * 32;
    int tx = threadIdx.x, ty = threadIdx.y;
    #pragma unroll
    for (int j = 0; j < 32; j += 8)
        tile[ty + j][tx] = src[(size_t)(r0 + ty + j) * C + c0 + tx];
    __syncthreads();
    #pragma unroll
    for (int j = 0; j < 32; j += 8)
        dst[(size_t)(c0 + ty + j) * R + r0 + tx] = (bf16)tile[tx][ty + j];
}

// ---------------- bf16 MFMA GEMM, 128x128 tile, BK=32, register-prefetch pipeline ----------------
// A: [M][K] bf16 row-major.  Bt: [N][K] bf16 (W^T).  bias: [N] fp32.
// Pipeline: regs hold tile kt; store->LDS; barrier; issue loads for kt+1 (latency
// overlapped by the 16 MFMAs below); ds_read frags; MFMA; barrier.
// LDS stride 40 (80B): conflict-free ds_read_b128 / ds_write_b128 per half-wave.
template<bool FUSE_GELU>
__global__ __launch_bounds__(256) void k_gemm(const bf16* __restrict__ A, const bf16* __restrict__ Bt,
                                              const float* __restrict__ bias, int M, int N, int K,
                                              bf16* __restrict__ outb, float* __restrict__ outf) {
    __shared__ __align__(16) bf16 lA[128 * LDST];
    __shared__ __align__(16) bf16 lB[128 * LDST];
    int t = threadIdx.x;
    int m0 = blockIdx.x * 128, n0 = blockIdx.y * 128;
    int w = t >> 6, l = t & 63;
    int wm = (w & 1) * 64, wn = (w >> 1) * 64;
    int lr = l & 15, lq = l >> 4;
    f32x4 acc[4][4];
    #pragma unroll
    for (int i = 0; i < 4; i++)
        #pragma unroll
        for (int j = 0; j < 4; j++)
            acc[i][j] = (f32x4){0.f, 0.f, 0.f, 0.f};
    int r0 = t >> 2;          // 0..63
    int ks = t & 3;
    const bf16* pa  = A  + (size_t)(m0 + r0) * K + ks * 8;
    const bf16* pa2 = pa + (size_t)64 * K;
    const bf16* pb  = Bt + (size_t)(n0 + r0) * K + ks * 8;
    const bf16* pb2 = pb + (size_t)64 * K;
    uint4 ra0 = *(const uint4*)pa;
    uint4 ra1 = *(const uint4*)pa2;
    uint4 rb0 = *(const uint4*)pb;
    uint4 rb1 = *(const uint4*)pb2;
    int nk = K / 32;
    for (int kt = 0; kt < nk; kt++) {
        *(uint4*)&lA[r0 * LDST + ks * 8] = ra0;
        *(uint4*)&lA[(r0 + 64) * LDST + ks * 8] = ra1;
        *(uint4*)&lB[r0 * LDST + ks * 8] = rb0;
        *(uint4*)&lB[(r0 + 64) * LDST + ks * 8] = rb1;
        __syncthreads();
        if (kt + 1 < nk) {
            int ko = (kt + 1) * 32;
            ra0 = *(const uint4*)(pa + ko);
            ra1 = *(const uint4*)(pa2 + ko);
            rb0 = *(const uint4*)(pb + ko);
            rb1 = *(const uint4*)(pb2 + ko);
        }
        bf16x8 af[4], bfv[4];
        #pragma unroll
        for (int mi = 0; mi < 4; mi++) af[mi]  = *(bf16x8*)&lA[(wm + mi * 16 + lr) * LDST + lq * 8];
        #pragma unroll
        for (int ni = 0; ni < 4; ni++) bfv[ni] = *(bf16x8*)&lB[(wn + ni * 16 + lr) * LDST + lq * 8];
        #pragma unroll
        for (int mi = 0; mi < 4; mi++)
            #pragma unroll
            for (int ni = 0; ni < 4; ni++)
                acc[mi][ni] = __builtin_amdgcn_mfma_f32_16x16x32_bf16(af[mi], bfv[ni], acc[mi][ni], 0, 0, 0);
        __syncthreads();
    }
    #pragma unroll
    for (int mi = 0; mi < 4; mi++) {
        #pragma unroll
        for (int ni = 0; ni < 4; ni++) {
            int col = n0 + wn + ni * 16 + lr;
            float bv = bias[col];
            #pragma unroll
            for (int r = 0; r < 4; r++) {
                int row = m0 + wm + mi * 16 + lq * 4 + r;
                float v = acc[mi][ni][r] + bv;
                if (FUSE_GELU) {
                    outb[(size_t)row * N + col] = (bf16)gelu_exact(v);
                } else {
                    size_t oo = (size_t)row * N + col;
                    outf[oo] = v + outf[oo];
                }
            }
        }
    }
}

extern "C" void kernel_launch(void* const* d_in, const int* in_sizes, int n_in,
                              void* d_out, int out_size, void* d_ws, size_t ws_size,
                              hipStream_t stream) {
    const float* input = (const float*)d_in[0];
    const float* w1    = (const float*)d_in[1];
    const float* b1    = (const float*)d_in[2];
    const float* w2    = (const float*)d_in[3];
    const float* b2    = (const float*)d_in[4];
    const float* ln1g  = (const float*)d_in[5];
    const float* ln1b  = (const float*)d_in[6];
    const float* ln2g  = (const float*)d_in[7];
    const float* ln2b  = (const float*)d_in[8];
    const float* mw1   = (const float*)d_in[9];
    const float* mb1   = (const float*)d_in[10];
    const float* mw2   = (const float*)d_in[11];
    const float* mb2   = (const float*)d_in[12];
    float* out = (float*)d_out;

    // ---- workspace layout ----
    // phase 1: [mu|rs | gre | gim | fr | fi]  (66.2 MB)
    // phase 2 (aliases):[mu|rs | lnA(bf16) | w1T | w2T | mid(bf16)]
    float* ws = (float*)d_ws;
    float* mu  = ws;                       // 16384
    float* rs  = ws + 16384;               // 16384
    const size_t BASE = 32768;
    float* gre = ws + BASE;                // 4,718,592
    float* gim = gre + 4718592;            // 4,718,592
    float* fr  = ws + BASE + 2 * 4718592;  // 3,538,944
    float* fi  = fr + 3538944;             // 3,538,944
    bf16* lnA = (bf16*)(ws + BASE);                  // 12,582,912 bf16
    bf16* w1T = (bf16*)(ws + BASE + 6291456);        //  2,359,296 bf16
    bf16* w2T = (bf16*)(ws + BASE + 7471104);        //  2,359,296 bf16
    bf16* mid = (bf16*)(ws + BASE + 8650752);        // up to 16384x3072 bf16

    // chunk count for channel-MLP, from ws_size (constant across calls -> graph-safe)
    const size_t fixed_fl = BASE + 6291456 + 1179648 + 1179648;   // 8,683,520 floats
    size_t avail_fl = ws_size / 4;
    int nch;
    if      (avail_fl >= fixed_fl + 25165824) nch = 1;   // mid = 16384x3072
    else if (avail_fl >= fixed_fl + 12582912) nch = 2;   // mid =  8192x3072
    else                                      nch = 4;   // mid =  4096x3072
    int MC = 16384 / nch;

    k_ln_stats<<<16384, 256, 0, stream>>>(input, mu, rs);
    k_dft_y<<<BT_ * 32 * 3, 256, 0, stream>>>(input, mu, rs, ln1g, ln1b, gre, gim);
    k_dft_x<<<BT_ * KM_ * 3, 256, 0, stream>>>(gre, gim, fr, fi);
    k_blockmlp<<<NB_ * 36, 256, 0, stream>>>(fr, fi, w1, b1, w2, b2);
    k_idft_x<<<BT_ * KM_ * 3, 256, 0, stream>>>(fr, fi, gre, gim);   // gre/gim now hold Z
    k_idft_y_res<<<BT_ * 32 * 3, 256, 0, stream>>>(gre, gim, input, mu, rs, ln1g, ln1b, out);
    k_ln2<<<16384, 256, 0, stream>>>(out, ln2g, ln2b, lnA);
    k_transpose_cast<<<dim3(3072 / 32, 768 / 32), dim3(32, 8), 0, stream>>>(mw1, w1T, 768, 3072);
    k_transpose_cast<<<dim3(768 / 32, 3072 / 32), dim3(32, 8), 0, stream>>>(mw2, w2T, 3072, 768);
    for (int c = 0; c < nch; c++) {
        const bf16* aC = lnA + (size_t)c * MC * 768;
        float* oC = out + (size_t)c * MC * 768;
        k_gemm<true><<<dim3(MC / 128, 24), 256, 0, stream>>>(aC, w1T, mb1, MC, 3072, 768, mid, nullptr);
        k_gemm<false><<<dim3(MC / 128, 6), 256, 0, stream>>>(mid, w2T, mb2, MC, 768, 3072, nullptr, oC);
    }
}